// Round 14
// baseline (371.409 us; speedup 1.0000x reference)
//
#include <hip/hip_runtime.h>
#include <hip/hip_bf16.h>

typedef __attribute__((ext_vector_type(8))) short bf16x8;
typedef __attribute__((ext_vector_type(4))) float f32x4;

typedef const __attribute__((address_space(1))) void gv_t;
typedef __attribute__((address_space(3))) void lv_t;
#define GLL16(g, l) __builtin_amdgcn_global_load_lds((gv_t*)(g), (lv_t*)(l), 16, 0, 0)

#define WAITV6()  asm volatile("s_waitcnt vmcnt(6)" ::: "memory")
#define WAITV0()  asm volatile("s_waitcnt vmcnt(0)" ::: "memory")
#define WAITL0()  asm volatile("s_waitcnt lgkmcnt(0)" ::: "memory")
#define SCHEDB()  __builtin_amdgcn_sched_barrier(0)
#define BARRAW()  __builtin_amdgcn_s_barrier()

__device__ __forceinline__ short f2bf(float f) {
    __hip_bfloat16 h = __float2bfloat16(f);
    return *reinterpret_cast<short*>(&h);
}

__device__ __forceinline__ float wred(float v) {
    #pragma unroll
    for (int m = 1; m < 64; m <<= 1) v += __shfl_xor(v, m);
    return v;
}

// ---------------- fp32 -> bf16 convert (weights) ----------------
__global__ __launch_bounds__(256) void cvt_kernel(const float* __restrict__ in,
                                                  short* __restrict__ out, int n4) {
    int i = blockIdx.x * 256 + threadIdx.x;
    if (i < n4) {
        float4 v = ((const float4*)in)[i];
        short4 o;
        o.x = f2bf(v.x); o.y = f2bf(v.y); o.z = f2bf(v.z); o.w = f2bf(v.w);
        ((short4*)out)[i] = o;
    }
}

// ---------------- LayerNorm (fp32 in, bf16 out), row = 1024 ----------------
__global__ __launch_bounds__(256) void ln_kernel(const float* __restrict__ x,
                                                 const float* __restrict__ g,
                                                 short* __restrict__ y) {
    const int row = blockIdx.x, tid = threadIdx.x;
    const float4 v = ((const float4*)(x + (size_t)row * 1024))[tid];
    float s = v.x + v.y + v.z + v.w;
    float s2 = v.x * v.x + v.y * v.y + v.z * v.z + v.w * v.w;
    #pragma unroll
    for (int m = 1; m < 64; m <<= 1) { s += __shfl_xor(s, m); s2 += __shfl_xor(s2, m); }
    __shared__ float rs[4], rs2[4];
    if ((tid & 63) == 0) { rs[tid >> 6] = s; rs2[tid >> 6] = s2; }
    __syncthreads();
    s = rs[0] + rs[1] + rs[2] + rs[3];
    s2 = rs2[0] + rs2[1] + rs2[2] + rs2[3];
    const float mean = s * (1.0f / 1024.0f);
    const float var = s2 * (1.0f / 1024.0f) - mean * mean;
    const float r = rsqrtf(var + 1e-5f);
    const float4 gg = ((const float4*)g)[tid];
    short4 o;
    o.x = f2bf((v.x - mean) * r * gg.x);
    o.y = f2bf((v.y - mean) * r * gg.y);
    o.z = f2bf((v.z - mean) * r * gg.z);
    o.w = f2bf((v.w - mean) * r * gg.w);
    ((short4*)y)[(size_t)row * 256 + tid] = o;
}

// ---------------- GEMM: C[M,N] = A[M,K] * B[N,K]^T, bf16 in ------------------------
// 128(m) x 256(n) block, 4 waves in 2x2, wave tile 64x128 (acc 4x8): 43.7 FLOP per
// LDS-read byte (1.33x better than 64x64 — r7-r12 were LDS-port-bound).  BK=32,
// double-buffered (48 KB LDS), VGPR<256 -> 2 blocks/CU.  r9-verified counted-vmcnt
// loop (6 loads/stage -> vmcnt(6) keeps newest stage in flight across barriers).
// 64B LDS rows: XOR swizzle slot ^= (row>>2)&3 -> quarter-wave b128 reads are
// 2-way per bank-group (free, m136).  Split-K via blockIdx.z.
// EPI 0: QKV split -> q (1/8), k, vT   EPI 1: fp32 (o0/o1 per z)   EPI 2: GELU bf16
template <int EPI>
__global__ __launch_bounds__(256, 2) void gemm_bt(const short* __restrict__ A,
                                                  const short* __restrict__ Bw,
                                                  int M, int N, int LDK, int KL,
                                                  void* __restrict__ o0,
                                                  void* __restrict__ o1,
                                                  void* __restrict__ o2) {
    __shared__ __align__(16) short As[2][128 * 32];   // 16 KB
    __shared__ __align__(16) short Bs[2][256 * 32];   // 32 KB
    const int tid = threadIdx.x;
    const int wid = tid >> 6, lane = tid & 63;
    const int wm = wid >> 1, wn = wid & 1;
    const int col = lane & 15, grp = lane >> 4;
    const int m0 = blockIdx.x * 128, n0 = blockIdx.y * 256;
    const int z = blockIdx.z;
    f32x4 acc[4][8] = {};
    const short* ga = A + (size_t)m0 * LDK + (size_t)z * KL;
    const short* gb = Bw + (size_t)n0 * LDK + (size_t)z * KL;

    // stage K-step t_ into buffer b_.  A: 128x32 (2 rounds), B: 256x32 (4 rounds);
    // 6 loads/thread.  LDS dest linear; swizzle on GLOBAL source k-slot.
#define GSTAGE(b_, t_) do {                                                     \
        const int k0_ = (t_) * 32;                                              \
        _Pragma("unroll")                                                       \
        for (int c = 0; c < 2; ++c) {                                           \
            const int row = c * 64 + (tid >> 2);                                \
            const int slot = (tid & 3) ^ ((row >> 2) & 3);                      \
            GLL16(ga + (size_t)row * LDK + k0_ + slot * 8,                      \
                  (char*)&As[b_][0] + c * 4096 + wid * 1024);                   \
        }                                                                       \
        _Pragma("unroll")                                                       \
        for (int c = 0; c < 4; ++c) {                                           \
            const int row = c * 64 + (tid >> 2);                                \
            const int slot = (tid & 3) ^ ((row >> 2) & 3);                      \
            GLL16(gb + (size_t)row * LDK + k0_ + slot * 8,                      \
                  (char*)&Bs[b_][0] + c * 4096 + wid * 1024);                   \
        }                                                                       \
    } while (0)

    const int NT = KL >> 5;
    GSTAGE(0, 0);
    GSTAGE(1, 1);
    WAITV6(); SCHEDB();       // stage 0 landed (stage 1 in flight)
    BARRAW();
    int cur = 0;
    for (int t = 0; t < NT; ++t) {
        const char* At = (const char*)&As[cur][0];
        const char* Bt = (const char*)&Bs[cur][0];
        bf16x8 af[4], bfr[8];
        #pragma unroll
        for (int i = 0; i < 4; ++i) {
            const int rowA = wm * 64 + i * 16 + col;
            af[i] = *(const bf16x8*)(At + rowA * 64 + ((grp ^ ((rowA >> 2) & 3)) << 4));
        }
        #pragma unroll
        for (int j = 0; j < 8; ++j) {
            const int rowB = wn * 128 + j * 16 + col;
            bfr[j] = *(const bf16x8*)(Bt + rowB * 64 + ((grp ^ ((rowB >> 2) & 3)) << 4));
        }
        WAITL0(); SCHEDB();      // reads retired -> WAR-safe to overwrite after barrier
        BARRAW();
        if (t + 2 < NT) GSTAGE(cur, t + 2);
        #pragma unroll
        for (int mi = 0; mi < 4; ++mi)
            #pragma unroll
            for (int nj = 0; nj < 8; ++nj)
                acc[mi][nj] = __builtin_amdgcn_mfma_f32_16x16x32_bf16(af[mi], bfr[nj], acc[mi][nj], 0, 0, 0);
        if (t + 1 < NT) {
            if (t + 2 < NT) { WAITV6(); } else { WAITV0(); }   // t+1 stage landed
            SCHEDB();
            BARRAW();
        }
        cur ^= 1;
    }
#undef GSTAGE
    #pragma unroll
    for (int mi = 0; mi < 4; ++mi) {
        #pragma unroll
        for (int nj = 0; nj < 8; ++nj) {
            #pragma unroll
            for (int i = 0; i < 4; ++i) {
                const int m = m0 + wm * 64 + mi * 16 + grp * 4 + i;
                const int n = n0 + wn * 128 + nj * 16 + col;
                const float v = acc[mi][nj][i];
                if (EPI == 0) {
                    const int b = m >> 11, t = m & 2047;
                    const int which = n >> 10, nn = n & 1023;
                    const int h = nn >> 6, d = nn & 63;
                    const size_t bh = (size_t)(b * 16 + h);
                    if (which == 0)
                        ((short*)o0)[(bh * 2048 + t) * 64 + d] = f2bf(v * 0.125f);
                    else if (which == 1)
                        ((short*)o1)[(bh * 2048 + t) * 64 + d] = f2bf(v);
                    else
                        ((short*)o2)[(bh * 64 + d) * 2048 + t] = f2bf(v);
                } else if (EPI == 1) {
                    float* dst = (z == 0) ? (float*)o0 : (float*)o1;
                    dst[(size_t)m * N + n] = v;
                } else {
                    const float gl = 0.5f * v * (1.0f + erff(v * 0.70710678118654752f));
                    ((short*)o0)[(size_t)m * N + n] = f2bf(gl);
                }
            }
        }
    }
}

// ---------------- Flash attention, causal, LDS-staged K/V, 64-row q-tile ----------
// (unchanged — verified)
__global__ __launch_bounds__(256, 3) void attn_kernel(const short* __restrict__ Q,
                                                      const short* __restrict__ Kg,
                                                      const short* __restrict__ VT,
                                                      short* __restrict__ Y) {
    __shared__ __align__(16) short Ks[2][4096];
    __shared__ __align__(16) short Vs[2][4096];
    __shared__ __align__(16) short Plds[4][16 * 72];
    const int j = 31 - blockIdx.x;
    const int bh = blockIdx.y;
    const int tid = threadIdx.x, wid = tid >> 6, lane = tid & 63;
    const int ql = lane & 15, g = lane >> 4;
    const int r8 = lane >> 3, s8 = lane & 7;
    const int q0s = j * 64 + wid * 16;
    const int lt = j;
    const short* Qb = Q + (size_t)bh * 2048 * 64;
    const short* Kb = Kg + (size_t)bh * 2048 * 64;
    const short* Vb = VT + (size_t)bh * 64 * 2048;
    short* Pw = &Plds[wid][0];

    bf16x8 qf0 = *(const bf16x8*)&Qb[(size_t)(q0s + ql) * 64 + 8 * g];
    bf16x8 qf1 = *(const bf16x8*)&Qb[(size_t)(q0s + ql) * 64 + 32 + 8 * g];
    f32x4 o[4] = {};
    float m = -1e30f, lsum = 0.0f;

#define STAGE(b_, kt_) do {                                                      \
        const int kbase_ = (kt_) * 64;                                           \
        _Pragma("unroll")                                                        \
        for (int c = 0; c < 2; ++c) {                                            \
            const int row = c * 32 + wid * 8 + r8;                               \
            const int slot = s8 ^ (row & 7);                                     \
            GLL16(Kb + (size_t)(kbase_ + row) * 64 + slot * 8,                   \
                  (char*)&Ks[b_][0] + c * 4096 + wid * 1024);                    \
            GLL16(Vb + (size_t)row * 2048 + kbase_ + slot * 8,                   \
                  (char*)&Vs[b_][0] + c * 4096 + wid * 1024);                    \
        }                                                                        \
    } while (0)

    STAGE(0, 0);
    __syncthreads();
    int buf = 0;
    for (int kt = 0; kt <= lt; ++kt) {
        if (kt < lt) STAGE(buf ^ 1, kt + 1);
        const int kbase = kt * 64;
        const short* Kt = &Ks[buf][0];
        const short* Vt = &Vs[buf][0];
        bf16x8 kf[4][2];
        #pragma unroll
        for (int kb = 0; kb < 4; ++kb) {
            const int row = 16 * kb + ql;
            const int x = row & 7;
            kf[kb][0] = *(const bf16x8*)((const char*)Kt + row * 128 + ((g ^ x) << 4));
            kf[kb][1] = *(const bf16x8*)((const char*)Kt + row * 128 + (((4 + g) ^ x) << 4));
        }
        f32x4 s[4];
        #pragma unroll
        for (int kb = 0; kb < 4; ++kb) {
            f32x4 z = {0.f, 0.f, 0.f, 0.f};
            z = __builtin_amdgcn_mfma_f32_16x16x32_bf16(kf[kb][0], qf0, z, 0, 0, 0);
            z = __builtin_amdgcn_mfma_f32_16x16x32_bf16(kf[kb][1], qf1, z, 0, 0, 0);
            s[kb] = z;
        }
        if (kbase + 63 > q0s) {
            #pragma unroll
            for (int kb = 0; kb < 4; ++kb)
                #pragma unroll
                for (int r = 0; r < 4; ++r)
                    if (kbase + 16 * kb + 4 * g + r > q0s + ql) s[kb][r] = -1e30f;
        }
        float t0 = fmaxf(fmaxf(s[0][0], s[0][1]), fmaxf(s[0][2], s[0][3]));
        float t1 = fmaxf(fmaxf(s[1][0], s[1][1]), fmaxf(s[1][2], s[1][3]));
        float t2 = fmaxf(fmaxf(s[2][0], s[2][1]), fmaxf(s[2][2], s[2][3]));
        float t3 = fmaxf(fmaxf(s[3][0], s[3][1]), fmaxf(s[3][2], s[3][3]));
        float tmax = fmaxf(fmaxf(t0, t1), fmaxf(t2, t3));
        tmax = fmaxf(tmax, __shfl_xor(tmax, 16));
        tmax = fmaxf(tmax, __shfl_xor(tmax, 32));
        const float mnew = fmaxf(m, tmax);
        const float sc = __expf(m - mnew);
        m = mnew;
        float rsum = 0.0f;
        #pragma unroll
        for (int kb = 0; kb < 4; ++kb) {
            const float e0 = __expf(s[kb][0] - mnew);
            const float e1 = __expf(s[kb][1] - mnew);
            const float e2 = __expf(s[kb][2] - mnew);
            const float e3 = __expf(s[kb][3] - mnew);
            rsum += (e0 + e1) + (e2 + e3);
            short4 pk;
            pk.x = f2bf(e0); pk.y = f2bf(e1); pk.z = f2bf(e2); pk.w = f2bf(e3);
            *(short4*)&Pw[ql * 72 + 16 * kb + 4 * g] = pk;
        }
        rsum += __shfl_xor(rsum, 16);
        rsum += __shfl_xor(rsum, 32);
        lsum = lsum * sc + rsum;
        #pragma unroll
        for (int nf = 0; nf < 4; ++nf)
            #pragma unroll
            for (int r = 0; r < 4; ++r) o[nf][r] *= sc;
        const bf16x8 pb0 = *(const bf16x8*)&Pw[ql * 72 + 8 * g];
        const bf16x8 pb1 = *(const bf16x8*)&Pw[ql * 72 + 32 + 8 * g];
        #pragma unroll
        for (int nf = 0; nf < 4; ++nf) {
            const int row = 16 * nf + ql;
            const int x = row & 7;
            bf16x8 v0 = *(const bf16x8*)((const char*)Vt + row * 128 + ((g ^ x) << 4));
            bf16x8 v1 = *(const bf16x8*)((const char*)Vt + row * 128 + (((4 + g) ^ x) << 4));
            o[nf] = __builtin_amdgcn_mfma_f32_16x16x32_bf16(v0, pb0, o[nf], 0, 0, 0);
            o[nf] = __builtin_amdgcn_mfma_f32_16x16x32_bf16(v1, pb1, o[nf], 0, 0, 0);
        }
        __syncthreads();
        buf ^= 1;
    }
#undef STAGE
    const int b = bh >> 4, h = bh & 15;
    const float inv = 1.0f / lsum;
    const size_t rowoff = ((size_t)b * 2048 + q0s + ql) * 1024 + h * 64;
    #pragma unroll
    for (int nf = 0; nf < 4; ++nf) {
        short4 w;
        w.x = f2bf(o[nf][0] * inv);
        w.y = f2bf(o[nf][1] * inv);
        w.z = f2bf(o[nf][2] * inv);
        w.w = f2bf(o[nf][3] * inv);
        *(short4*)&Y[rowoff + 16 * nf + 4 * g] = w;
    }
}

// ---------------- Hyperbolic residual: out = expmap(x, va+vb, c), per-head wave ---
__global__ __launch_bounds__(256) void expmap_kernel(const float* __restrict__ x,
                                                     const float* __restrict__ va,
                                                     const float* __restrict__ vb,
                                                     const float* __restrict__ carr,
                                                     float* __restrict__ out) {
    const int blk = blockIdx.x;
    const int row = blk >> 2;
    const int head = (blk & 3) * 4 + (threadIdx.x >> 6);
    const int lane = threadIdx.x & 63;
    const size_t idx = (size_t)row * 1024 + head * 64 + lane;
    float c = carr[head];
    c = fminf(fmaxf(c, 1e-4f), 1.0f);
    const float xe = x[idx], ve = va[idx] + vb[idx];
    const float xn = wred(xe * xe);
    const float vns = wred(ve * ve);
    const float vn = sqrtf(vns + 1e-9f);
    const float sf = 2.0f / (1.0f + c * xn + 1e-9f);
    const float targ = fabsf(0.5f * c * sf * vns);
    const float coeff = (1.0f / (sqrtf(c + 1e-9f) + 1e-9f)) * tanhf(sqrtf(targ + 1e-9f));
    const float ye = coeff * ve / (vn + 1e-9f);
    const float yn = wred(ye * ye);
    const float ip = wred(xe * ye);
    const float num = (1.0f + 2.0f * c * ip + c * yn) * xe + (1.0f - c * xn) * ye;
    const float den = 1.0f + 2.0f * c * ip + c * c * xn * yn;
    out[idx] = num / (den + 1e-9f);
}

extern "C" void kernel_launch(void* const* d_in, const int* in_sizes, int n_in,
                              void* d_out, int out_size, void* d_ws, size_t ws_size,
                              hipStream_t stream) {
    (void)in_sizes; (void)n_in; (void)out_size; (void)ws_size;
    const float* x      = (const float*)d_in[0];
    const float* ln1_g  = (const float*)d_in[1];
    const float* w_qkv  = (const float*)d_in[2];
    const float* w_proj = (const float*)d_in[3];
    const float* c_attn = (const float*)d_in[4];
    const float* ln2_g  = (const float*)d_in[5];
    const float* w_fc   = (const float*)d_in[6];
    const float* w_mlp  = (const float*)d_in[7];
    const float* c_mlp  = (const float*)d_in[8];
    float* out = (float*)d_out;
    char* ws = (char*)d_ws;
    const size_t MB = 1024 * 1024;

    short* wqkv_bf  = (short*)(ws + 0 * MB);    // [cvt -> QKV]
    short* wproj_bf = (short*)(ws + 6 * MB);    // [cvt -> proj]
    short* wfc_bf   = (short*)(ws + 8 * MB);    // [cvt -> FC]
    short* wmlp_bf  = (short*)(ws + 16 * MB);   // [cvt -> MLP]
    short* y_bf     = (short*)(ws + 24 * MB);   // [ln1 -> QKV], [ln2 -> FC]
    short* q_bf     = (short*)(ws + 32 * MB);   // [QKV -> attn]
    short* k_bf     = (short*)(ws + 40 * MB);   // [QKV -> attn]
    short* vT_bf    = (short*)(ws + 48 * MB);   // [QKV -> attn]
    short* att_bf   = (short*)(ws + 56 * MB);   // [attn -> proj]
    float* a0       = (float*)(ws + 64 * MB);   // [proj -> expmap1]
    float* a1       = (float*)(ws + 80 * MB);   // [proj -> expmap1]
    float* x1       = (float*)(ws + 40 * MB);   // [expmap1 -> expmap2] (over k,vT)
    short* g_bf     = (short*)(ws + 56 * MB);   // [FC -> MLP] 32MB (over att,a0,a1[0:8])
    float* h0       = (float*)(ws + 0 * MB);    // [MLP -> expmap2] (over wqkv,wproj,wfc)
    float* h1       = (float*)(ws + 24 * MB);   // [MLP -> expmap2] (over y_bf,q_bf)

    cvt_kernel<<<3072, 256, 0, stream>>>(w_qkv, wqkv_bf, 3072 * 1024 / 4);
    cvt_kernel<<<1024, 256, 0, stream>>>(w_proj, wproj_bf, 1024 * 1024 / 4);
    cvt_kernel<<<4096, 256, 0, stream>>>(w_fc, wfc_bf, 4096 * 1024 / 4);
    cvt_kernel<<<4096, 256, 0, stream>>>(w_mlp, wmlp_bf, 1024 * 4096 / 4);

    ln_kernel<<<4096, 256, 0, stream>>>(x, ln1_g, y_bf);
    gemm_bt<0><<<dim3(32, 12, 1), 256, 0, stream>>>(y_bf, wqkv_bf, 4096, 3072, 1024, 1024,
                                                    q_bf, k_bf, vT_bf);
    attn_kernel<<<dim3(32, 32), 256, 0, stream>>>(q_bf, k_bf, vT_bf, att_bf);
    gemm_bt<1><<<dim3(32, 4, 2), 256, 0, stream>>>(att_bf, wproj_bf, 4096, 1024, 1024, 512,
                                                   a0, a1, nullptr);
    expmap_kernel<<<16384, 256, 0, stream>>>(x, a0, a1, c_attn, x1);
    ln_kernel<<<4096, 256, 0, stream>>>(x1, ln2_g, y_bf);
    gemm_bt<2><<<dim3(32, 16, 1), 256, 0, stream>>>(y_bf, wfc_bf, 4096, 4096, 1024, 1024,
                                                    g_bf, nullptr, nullptr);
    gemm_bt<1><<<dim3(32, 4, 2), 256, 0, stream>>>(g_bf, wmlp_bf, 4096, 1024, 4096, 2048,
                                                   h0, h1, nullptr);
    expmap_kernel<<<16384, 256, 0, stream>>>(x1, h0, h1, c_mlp, out);
}

// Round 15
// 343.251 us; speedup vs baseline: 1.0820x; 1.0820x over previous
//
#include <hip/hip_runtime.h>
#include <hip/hip_bf16.h>

typedef __attribute__((ext_vector_type(8))) short bf16x8;
typedef __attribute__((ext_vector_type(4))) float f32x4;

typedef const __attribute__((address_space(1))) void gv_t;
typedef __attribute__((address_space(3))) void lv_t;
#define GLL16(g, l) __builtin_amdgcn_global_load_lds((gv_t*)(g), (lv_t*)(l), 16, 0, 0)

#define WAITV8()  asm volatile("s_waitcnt vmcnt(8)" ::: "memory")
#define WAITV4()  asm volatile("s_waitcnt vmcnt(4)" ::: "memory")
#define WAITV0()  asm volatile("s_waitcnt vmcnt(0)" ::: "memory")
#define WAITL0()  asm volatile("s_waitcnt lgkmcnt(0)" ::: "memory")
#define SCHEDB()  __builtin_amdgcn_sched_barrier(0)
#define BARRAW()  __builtin_amdgcn_s_barrier()

__device__ __forceinline__ short f2bf(float f) {
    __hip_bfloat16 h = __float2bfloat16(f);
    return *reinterpret_cast<short*>(&h);
}

__device__ __forceinline__ float wred(float v) {
    #pragma unroll
    for (int m = 1; m < 64; m <<= 1) v += __shfl_xor(v, m);
    return v;
}

// frag read with the r12-verified XOR swizzle (slot ^= row&7, 128B rows)
__device__ __forceinline__ bf16x8 ldsfrag(const short* buf, int rin, int slot) {
    const int s = slot ^ (rin & 7);
    return *(const bf16x8*)((const char*)buf + rin * 128 + (s << 4));
}

// ---------------- fp32 -> bf16 convert (weights) ----------------
__global__ __launch_bounds__(256) void cvt_kernel(const float* __restrict__ in,
                                                  short* __restrict__ out, int n4) {
    int i = blockIdx.x * 256 + threadIdx.x;
    if (i < n4) {
        float4 v = ((const float4*)in)[i];
        short4 o;
        o.x = f2bf(v.x); o.y = f2bf(v.y); o.z = f2bf(v.z); o.w = f2bf(v.w);
        ((short4*)out)[i] = o;
    }
}

// ---------------- LayerNorm (fp32 in, bf16 out), row = 1024 ----------------
__global__ __launch_bounds__(256) void ln_kernel(const float* __restrict__ x,
                                                 const float* __restrict__ g,
                                                 short* __restrict__ y) {
    const int row = blockIdx.x, tid = threadIdx.x;
    const float4 v = ((const float4*)(x + (size_t)row * 1024))[tid];
    float s = v.x + v.y + v.z + v.w;
    float s2 = v.x * v.x + v.y * v.y + v.z * v.z + v.w * v.w;
    #pragma unroll
    for (int m = 1; m < 64; m <<= 1) { s += __shfl_xor(s, m); s2 += __shfl_xor(s2, m); }
    __shared__ float rs[4], rs2[4];
    if ((tid & 63) == 0) { rs[tid >> 6] = s; rs2[tid >> 6] = s2; }
    __syncthreads();
    s = rs[0] + rs[1] + rs[2] + rs[3];
    s2 = rs2[0] + rs2[1] + rs2[2] + rs2[3];
    const float mean = s * (1.0f / 1024.0f);
    const float var = s2 * (1.0f / 1024.0f) - mean * mean;
    const float r = rsqrtf(var + 1e-5f);
    const float4 gg = ((const float4*)g)[tid];
    short4 o;
    o.x = f2bf((v.x - mean) * r * gg.x);
    o.y = f2bf((v.y - mean) * r * gg.y);
    o.z = f2bf((v.z - mean) * r * gg.z);
    o.w = f2bf((v.w - mean) * r * gg.w);
    ((short4*)y)[(size_t)row * 256 + tid] = o;
}

// ---------------- GEMM 256x256, 8-phase counted-vmcnt schedule (T3+T4+T5) ---------
// 512 thr, 8 waves (2M x 4N), wave tile 128x64 (acc 8x4).  BK=64.  LDS 128 KB as
// [dbuf][half] quarters of [128][64].  Per phase: ds-read subtile + stage ONE
// half-tile (2 loads/thr) + barrier + lgkmcnt(0) + setprio(1) 16 MFMA setprio(0)
// + barrier; vmcnt(4) only at phases 4/8 (T1/T2 landed, newest 2 halves remain in
// flight).  Staging ledger (iter i, tiles T0=2i dbuf0, T1 dbuf1, T2=2i+2, T3):
//   P1:A0(T1)  P2:A1(T1)  P3:B0(T2)  P4:B1(T2)  P5:A0(T2)  P6:A1(T2)
//   P7:B0(T3)  P8:B1(T3)
// WAR: each stage's target quarter was last read in the phase whose lgkmcnt+barrier
// precedes the stage's issue.  EPI 0: QKV split.  EPI 2: exact GELU -> bf16.
template <int EPI>
__global__ __launch_bounds__(512) void gemm8p(const short* __restrict__ A,
                                              const short* __restrict__ Bw,
                                              int M, int N, int LDK,
                                              void* __restrict__ o0,
                                              void* __restrict__ o1,
                                              void* __restrict__ o2) {
    __shared__ __align__(16) short As[2][2][128 * 64];   // [dbuf][half] 64 KB
    __shared__ __align__(16) short Bs[2][2][128 * 64];   // 64 KB
    const int tid = threadIdx.x;
    const int wid = tid >> 6, lane = tid & 63;
    const int wm = wid >> 2, wn = wid & 3;
    const int col = lane & 15, grp = lane >> 4;
    const int r8 = lane >> 3, s8 = lane & 7;
    const int m0 = blockIdx.x * 256, n0 = blockIdx.y * 256;
    f32x4 acc[8][4] = {};
    const short* ga = A + (size_t)m0 * LDK;
    const short* gb = Bw + (size_t)n0 * LDK;
    const short* myA[2] = { &As[0][wm][0], &As[1][wm][0] };
    const short* myB[2] = { &Bs[0][wn >> 1][0], &Bs[1][wn >> 1][0] };
    const int brow = (wn & 1) * 64;
    const int NT = LDK >> 6;

    // stage one half-tile (128 rows x 64 cols) -> linear LDS dest, swizzled source
#define STAGE_HALF(G_, rbase_, k0_, ldsbuf_) do {                               \
        _Pragma("unroll")                                                       \
        for (int c = 0; c < 2; ++c) {                                           \
            const int row = c * 64 + wid * 8 + r8;                              \
            const int slot = s8 ^ (row & 7);                                    \
            GLL16((G_) + (size_t)((rbase_) + row) * LDK + (k0_) + slot * 8,     \
                  (char*)(ldsbuf_) + c * 8192 + wid * 1024);                    \
        }                                                                       \
    } while (0)

#define READ_A(dsel, mibase)                                                    \
        _Pragma("unroll")                                                       \
        for (int j = 0; j < 2; ++j) {                                           \
            af[j][0] = ldsfrag(myA[dsel], (mibase + j) * 16 + col, grp);        \
            af[j][1] = ldsfrag(myA[dsel], (mibase + j) * 16 + col, 4 + grp);    \
        }

#define READ_B(dsel)                                                            \
        _Pragma("unroll")                                                       \
        for (int nj = 0; nj < 4; ++nj) {                                        \
            bf[nj][0] = ldsfrag(myB[dsel], brow + nj * 16 + col, grp);          \
            bf[nj][1] = ldsfrag(myB[dsel], brow + nj * 16 + col, 4 + grp);      \
        }

#define DO_MFMA(mibase)                                                         \
        __builtin_amdgcn_s_setprio(1);                                          \
        _Pragma("unroll")                                                       \
        for (int ks = 0; ks < 2; ++ks)                                          \
            _Pragma("unroll")                                                   \
            for (int j = 0; j < 2; ++j)                                         \
                _Pragma("unroll")                                               \
                for (int nj = 0; nj < 4; ++nj)                                  \
                    acc[mibase + j][nj] = __builtin_amdgcn_mfma_f32_16x16x32_bf16( \
                        af[j][ks], bf[nj][ks], acc[mibase + j][nj], 0, 0, 0);   \
        __builtin_amdgcn_s_setprio(0);

#define PHASE_SYNC_IN()  SCHEDB(); BARRAW(); WAITL0(); SCHEDB()
#define PHASE_SYNC_OUT() SCHEDB(); BARRAW()

    // prologue: A(T0), B(T0), B(T1) = 12 loads; keep B(T1)'s 4 in flight
    STAGE_HALF(ga, 0,   0,  &As[0][0][0]);
    STAGE_HALF(ga, 128, 0,  &As[0][1][0]);
    STAGE_HALF(gb, 0,   0,  &Bs[0][0][0]);
    STAGE_HALF(gb, 128, 0,  &Bs[0][1][0]);
    STAGE_HALF(gb, 0,   64, &Bs[1][0][0]);
    STAGE_HALF(gb, 128, 64, &Bs[1][1][0]);
    WAITV4(); SCHEDB();
    BARRAW();

    const int NIT = NT >> 1;
    for (int it = 0; it < NIT; ++it) {
        const int t1k = (2 * it + 1) << 6;
        const int t2k = (2 * it + 2) << 6;
        const int t3k = (2 * it + 3) << 6;
        const bool h2 = (2 * it + 2) < NT;
        const bool h3 = (2 * it + 3) < NT;
        bf16x8 bf[4][2], af[2][2];

        // ---- P1: dbuf0 B-all + A mi0-1; stage A0(T1)->dbuf1 ----
        READ_B(0) READ_A(0, 0)
        STAGE_HALF(ga, 0, t1k, &As[1][0][0]);
        PHASE_SYNC_IN(); DO_MFMA(0) PHASE_SYNC_OUT();
        // ---- P2: A mi2-3; stage A1(T1) ----
        READ_A(0, 2)
        STAGE_HALF(ga, 128, t1k, &As[1][1][0]);
        PHASE_SYNC_IN(); DO_MFMA(2) PHASE_SYNC_OUT();
        // ---- P3: A mi4-5; stage B0(T2)->dbuf0 ----
        READ_A(0, 4)
        if (h2) STAGE_HALF(gb, 0, t2k, &Bs[0][0][0]);
        PHASE_SYNC_IN(); DO_MFMA(4) PHASE_SYNC_OUT();
        // ---- P4: A mi6-7; stage B1(T2); vmcnt gates T1 reads ----
        READ_A(0, 6)
        if (h2) STAGE_HALF(gb, 128, t2k, &Bs[0][1][0]);
        PHASE_SYNC_IN(); DO_MFMA(6)
        if (h2) { WAITV4(); } else { WAITV0(); }
        PHASE_SYNC_OUT();
        // ---- P5: dbuf1 B-all + A mi0-1; stage A0(T2)->dbuf0 ----
        READ_B(1) READ_A(1, 0)
        if (h2) STAGE_HALF(ga, 0, t2k, &As[0][0][0]);
        PHASE_SYNC_IN(); DO_MFMA(0) PHASE_SYNC_OUT();
        // ---- P6: A mi2-3; stage A1(T2) ----
        READ_A(1, 2)
        if (h2) STAGE_HALF(ga, 128, t2k, &As[0][1][0]);
        PHASE_SYNC_IN(); DO_MFMA(2) PHASE_SYNC_OUT();
        // ---- P7: A mi4-5; stage B0(T3)->dbuf1 ----
        READ_A(1, 4)
        if (h3) STAGE_HALF(gb, 0, t3k, &Bs[1][0][0]);
        PHASE_SYNC_IN(); DO_MFMA(4) PHASE_SYNC_OUT();
        // ---- P8: A mi6-7; stage B1(T3); vmcnt gates T2 reads ----
        READ_A(1, 6)
        if (h3) STAGE_HALF(gb, 128, t3k, &Bs[1][1][0]);
        PHASE_SYNC_IN(); DO_MFMA(6)
        if (h3) { WAITV4(); } else { WAITV0(); }
        PHASE_SYNC_OUT();
    }
#undef STAGE_HALF
#undef READ_A
#undef READ_B
#undef DO_MFMA
#undef PHASE_SYNC_IN
#undef PHASE_SYNC_OUT
    #pragma unroll
    for (int mi = 0; mi < 8; ++mi) {
        #pragma unroll
        for (int nj = 0; nj < 4; ++nj) {
            #pragma unroll
            for (int i = 0; i < 4; ++i) {
                const int m = m0 + wm * 128 + mi * 16 + grp * 4 + i;
                const int n = n0 + wn * 64 + nj * 16 + col;
                const float v = acc[mi][nj][i];
                if (EPI == 0) {
                    const int b = m >> 11, t = m & 2047;
                    const int which = n >> 10, nn = n & 1023;
                    const int h = nn >> 6, d = nn & 63;
                    const size_t bh = (size_t)(b * 16 + h);
                    if (which == 0)
                        ((short*)o0)[(bh * 2048 + t) * 64 + d] = f2bf(v * 0.125f);
                    else if (which == 1)
                        ((short*)o1)[(bh * 2048 + t) * 64 + d] = f2bf(v);
                    else
                        ((short*)o2)[(bh * 64 + d) * 2048 + t] = f2bf(v);
                } else {
                    const float gl = 0.5f * v * (1.0f + erff(v * 0.70710678118654752f));
                    ((short*)o0)[(size_t)m * N + n] = f2bf(gl);
                }
            }
        }
    }
}

// ---------------- GEMM 128x128 (r12-verified): N=1024 ops (proj, MLP) -------------
// BK=64 dbuf, counted vmcnt(8), XOR-swizzled staging, XCD-chunked block swizzle
// (requires gridDim.x==32, gridDim.y%4==0).  Split-K via blockIdx.z; EPI1 fp32.
template <int EPI>
__global__ __launch_bounds__(256, 2) void gemm_bt(const short* __restrict__ A,
                                                  const short* __restrict__ Bw,
                                                  int M, int N, int LDK, int KL,
                                                  void* __restrict__ o0,
                                                  void* __restrict__ o1,
                                                  void* __restrict__ o2) {
    __shared__ __align__(16) short As[2][128 * 64];
    __shared__ __align__(16) short Bs[2][128 * 64];
    const int tid = threadIdx.x;
    const int wid = tid >> 6, lane = tid & 63;
    const int wm = wid >> 1, wn = wid & 1;
    const int col = lane & 15, grp = lane >> 4;
    const int r8 = lane >> 3, s8 = lane & 7;
    const int orig = blockIdx.x + (int)gridDim.x * blockIdx.y;
    const int xcd = orig & 7, idx = orig >> 3;
    const int NC = gridDim.y >> 2;
    const int mt = ((xcd >> 2) << 4) + (idx & 15);
    const int nt = (xcd & 3) * NC + (idx >> 4);
    const int m0 = mt * 128, n0 = nt * 128;
    const int z = blockIdx.z;
    f32x4 acc[4][4] = {};
    const short* ga = A + (size_t)m0 * LDK + (size_t)z * KL;
    const short* gb = Bw + (size_t)n0 * LDK + (size_t)z * KL;

#define GSTAGE(b_, t_) do {                                                     \
        const int k0_ = (t_) * 64;                                              \
        _Pragma("unroll")                                                       \
        for (int c = 0; c < 4; ++c) {                                           \
            const int row = c * 32 + wid * 8 + r8;                              \
            const int slot = s8 ^ (row & 7);                                    \
            GLL16(ga + (size_t)row * LDK + k0_ + slot * 8,                      \
                  (char*)&As[b_][0] + c * 4096 + wid * 1024);                   \
            GLL16(gb + (size_t)row * LDK + k0_ + slot * 8,                      \
                  (char*)&Bs[b_][0] + c * 4096 + wid * 1024);                   \
        }                                                                       \
    } while (0)

    const int NT = KL >> 6;
    GSTAGE(0, 0);
    if (NT > 1) { GSTAGE(1, 1); WAITV8(); } else { WAITV0(); }
    SCHEDB();
    BARRAW();
    int cur = 0;
    for (int t = 0; t < NT; ++t) {
        const char* At = (const char*)&As[cur][0];
        const char* Bt = (const char*)&Bs[cur][0];
        bf16x8 af[2][4], bfr[2][4];
        #pragma unroll
        for (int s = 0; s < 2; ++s)
            #pragma unroll
            for (int i = 0; i < 4; ++i) {
                const int rowA = wm * 64 + i * 16 + col;
                const int rowB = wn * 64 + i * 16 + col;
                af[s][i]  = *(const bf16x8*)(At + rowA * 128 + (((s * 4 + grp) ^ (rowA & 7)) << 4));
                bfr[s][i] = *(const bf16x8*)(Bt + rowB * 128 + (((s * 4 + grp) ^ (rowB & 7)) << 4));
            }
        WAITL0(); SCHEDB();
        BARRAW();
        if (t + 2 < NT) GSTAGE(cur, t + 2);
        #pragma unroll
        for (int s = 0; s < 2; ++s)
            #pragma unroll
            for (int mi = 0; mi < 4; ++mi)
                #pragma unroll
                for (int ni = 0; ni < 4; ++ni)
                    acc[mi][ni] = __builtin_amdgcn_mfma_f32_16x16x32_bf16(af[s][mi], bfr[s][ni], acc[mi][ni], 0, 0, 0);
        if (t + 1 < NT) {
            if (t + 2 < NT) { WAITV8(); } else { WAITV0(); }
            SCHEDB();
            BARRAW();
        }
        cur ^= 1;
    }
#undef GSTAGE
    #pragma unroll
    for (int mi = 0; mi < 4; ++mi) {
        #pragma unroll
        for (int ni = 0; ni < 4; ++ni) {
            #pragma unroll
            for (int i = 0; i < 4; ++i) {
                const int m = m0 + wm * 64 + mi * 16 + grp * 4 + i;
                const int n = n0 + wn * 64 + ni * 16 + col;
                const float v = acc[mi][ni][i];
                if (EPI == 1) {
                    float* dst = (z == 0) ? (float*)o0 : (float*)o1;
                    dst[(size_t)m * N + n] = v;
                } else {
                    const float gl = 0.5f * v * (1.0f + erff(v * 0.70710678118654752f));
                    ((short*)o0)[(size_t)m * N + n] = f2bf(gl);
                }
            }
        }
    }
}

// ---------------- Flash attention, causal, LDS-staged K/V, 64-row q-tile ----------
// (unchanged — verified)
__global__ __launch_bounds__(256, 3) void attn_kernel(const short* __restrict__ Q,
                                                      const short* __restrict__ Kg,
                                                      const short* __restrict__ VT,
                                                      short* __restrict__ Y) {
    __shared__ __align__(16) short Ks[2][4096];
    __shared__ __align__(16) short Vs[2][4096];
    __shared__ __align__(16) short Plds[4][16 * 72];
    const int j = 31 - blockIdx.x;
    const int bh = blockIdx.y;
    const int tid = threadIdx.x, wid = tid >> 6, lane = tid & 63;
    const int ql = lane & 15, g = lane >> 4;
    const int r8 = lane >> 3, s8 = lane & 7;
    const int q0s = j * 64 + wid * 16;
    const int lt = j;
    const short* Qb = Q + (size_t)bh * 2048 * 64;
    const short* Kb = Kg + (size_t)bh * 2048 * 64;
    const short* Vb = VT + (size_t)bh * 64 * 2048;
    short* Pw = &Plds[wid][0];

    bf16x8 qf0 = *(const bf16x8*)&Qb[(size_t)(q0s + ql) * 64 + 8 * g];
    bf16x8 qf1 = *(const bf16x8*)&Qb[(size_t)(q0s + ql) * 64 + 32 + 8 * g];
    f32x4 o[4] = {};
    float m = -1e30f, lsum = 0.0f;

#define STAGE(b_, kt_) do {                                                      \
        const int kbase_ = (kt_) * 64;                                           \
        _Pragma("unroll")                                                        \
        for (int c = 0; c < 2; ++c) {                                            \
            const int row = c * 32 + wid * 8 + r8;                               \
            const int slot = s8 ^ (row & 7);                                     \
            GLL16(Kb + (size_t)(kbase_ + row) * 64 + slot * 8,                   \
                  (char*)&Ks[b_][0] + c * 4096 + wid * 1024);                    \
            GLL16(Vb + (size_t)row * 2048 + kbase_ + slot * 8,                   \
                  (char*)&Vs[b_][0] + c * 4096 + wid * 1024);                    \
        }                                                                        \
    } while (0)

    STAGE(0, 0);
    __syncthreads();
    int buf = 0;
    for (int kt = 0; kt <= lt; ++kt) {
        if (kt < lt) STAGE(buf ^ 1, kt + 1);
        const int kbase = kt * 64;
        const short* Kt = &Ks[buf][0];
        const short* Vt = &Vs[buf][0];
        bf16x8 kf[4][2];
        #pragma unroll
        for (int kb = 0; kb < 4; ++kb) {
            const int row = 16 * kb + ql;
            const int x = row & 7;
            kf[kb][0] = *(const bf16x8*)((const char*)Kt + row * 128 + ((g ^ x) << 4));
            kf[kb][1] = *(const bf16x8*)((const char*)Kt + row * 128 + (((4 + g) ^ x) << 4));
        }
        f32x4 s[4];
        #pragma unroll
        for (int kb = 0; kb < 4; ++kb) {
            f32x4 z = {0.f, 0.f, 0.f, 0.f};
            z = __builtin_amdgcn_mfma_f32_16x16x32_bf16(kf[kb][0], qf0, z, 0, 0, 0);
            z = __builtin_amdgcn_mfma_f32_16x16x32_bf16(kf[kb][1], qf1, z, 0, 0, 0);
            s[kb] = z;
        }
        if (kbase + 63 > q0s) {
            #pragma unroll
            for (int kb = 0; kb < 4; ++kb)
                #pragma unroll
                for (int r = 0; r < 4; ++r)
                    if (kbase + 16 * kb + 4 * g + r > q0s + ql) s[kb][r] = -1e30f;
        }
        float t0 = fmaxf(fmaxf(s[0][0], s[0][1]), fmaxf(s[0][2], s[0][3]));
        float t1 = fmaxf(fmaxf(s[1][0], s[1][1]), fmaxf(s[1][2], s[1][3]));
        float t2 = fmaxf(fmaxf(s[2][0], s[2][1]), fmaxf(s[2][2], s[2][3]));
        float t3 = fmaxf(fmaxf(s[3][0], s[3][1]), fmaxf(s[3][2], s[3][3]));
        float tmax = fmaxf(fmaxf(t0, t1), fmaxf(t2, t3));
        tmax = fmaxf(tmax, __shfl_xor(tmax, 16));
        tmax = fmaxf(tmax, __shfl_xor(tmax, 32));
        const float mnew = fmaxf(m, tmax);
        const float sc = __expf(m - mnew);
        m = mnew;
        float rsum = 0.0f;
        #pragma unroll
        for (int kb = 0; kb < 4; ++kb) {
            const float e0 = __expf(s[kb][0] - mnew);
            const float e1 = __expf(s[kb][1] - mnew);
            const float e2 = __expf(s[kb][2] - mnew);
            const float e3 = __expf(s[kb][3] - mnew);
            rsum += (e0 + e1) + (e2 + e3);
            short4 pk;
            pk.x = f2bf(e0); pk.y = f2bf(e1); pk.z = f2bf(e2); pk.w = f2bf(e3);
            *(short4*)&Pw[ql * 72 + 16 * kb + 4 * g] = pk;
        }
        rsum += __shfl_xor(rsum, 16);
        rsum += __shfl_xor(rsum, 32);
        lsum = lsum * sc + rsum;
        #pragma unroll
        for (int nf = 0; nf < 4; ++nf)
            #pragma unroll
            for (int r = 0; r < 4; ++r) o[nf][r] *= sc;
        const bf16x8 pb0 = *(const bf16x8*)&Pw[ql * 72 + 8 * g];
        const bf16x8 pb1 = *(const bf16x8*)&Pw[ql * 72 + 32 + 8 * g];
        #pragma unroll
        for (int nf = 0; nf < 4; ++nf) {
            const int row = 16 * nf + ql;
            const int x = row & 7;
            bf16x8 v0 = *(const bf16x8*)((const char*)Vt + row * 128 + ((g ^ x) << 4));
            bf16x8 v1 = *(const bf16x8*)((const char*)Vt + row * 128 + (((4 + g) ^ x) << 4));
            o[nf] = __builtin_amdgcn_mfma_f32_16x16x32_bf16(v0, pb0, o[nf], 0, 0, 0);
            o[nf] = __builtin_amdgcn_mfma_f32_16x16x32_bf16(v1, pb1, o[nf], 0, 0, 0);
        }
        __syncthreads();
        buf ^= 1;
    }
#undef STAGE
    const int b = bh >> 4, h = bh & 15;
    const float inv = 1.0f / lsum;
    const size_t rowoff = ((size_t)b * 2048 + q0s + ql) * 1024 + h * 64;
    #pragma unroll
    for (int nf = 0; nf < 4; ++nf) {
        short4 w;
        w.x = f2bf(o[nf][0] * inv);
        w.y = f2bf(o[nf][1] * inv);
        w.z = f2bf(o[nf][2] * inv);
        w.w = f2bf(o[nf][3] * inv);
        *(short4*)&Y[rowoff + 16 * nf + 4 * g] = w;
    }
}

// ---------------- Hyperbolic residual: out = expmap(x, va+vb, c), per-head wave ---
__global__ __launch_bounds__(256) void expmap_kernel(const float* __restrict__ x,
                                                     const float* __restrict__ va,
                                                     const float* __restrict__ vb,
                                                     const float* __restrict__ carr,
                                                     float* __restrict__ out) {
    const int blk = blockIdx.x;
    const int row = blk >> 2;
    const int head = (blk & 3) * 4 + (threadIdx.x >> 6);
    const int lane = threadIdx.x & 63;
    const size_t idx = (size_t)row * 1024 + head * 64 + lane;
    float c = carr[head];
    c = fminf(fmaxf(c, 1e-4f), 1.0f);
    const float xe = x[idx], ve = va[idx] + vb[idx];
    const float xn = wred(xe * xe);
    const float vns = wred(ve * ve);
    const float vn = sqrtf(vns + 1e-9f);
    const float sf = 2.0f / (1.0f + c * xn + 1e-9f);
    const float targ = fabsf(0.5f * c * sf * vns);
    const float coeff = (1.0f / (sqrtf(c + 1e-9f) + 1e-9f)) * tanhf(sqrtf(targ + 1e-9f));
    const float ye = coeff * ve / (vn + 1e-9f);
    const float yn = wred(ye * ye);
    const float ip = wred(xe * ye);
    const float num = (1.0f + 2.0f * c * ip + c * yn) * xe + (1.0f - c * xn) * ye;
    const float den = 1.0f + 2.0f * c * ip + c * c * xn * yn;
    out[idx] = num / (den + 1e-9f);
}

extern "C" void kernel_launch(void* const* d_in, const int* in_sizes, int n_in,
                              void* d_out, int out_size, void* d_ws, size_t ws_size,
                              hipStream_t stream) {
    (void)in_sizes; (void)n_in; (void)out_size; (void)ws_size;
    const float* x      = (const float*)d_in[0];
    const float* ln1_g  = (const float*)d_in[1];
    const float* w_qkv  = (const float*)d_in[2];
    const float* w_proj = (const float*)d_in[3];
    const float* c_attn = (const float*)d_in[4];
    const float* ln2_g  = (const float*)d_in[5];
    const float* w_fc   = (const float*)d_in[6];
    const float* w_mlp  = (const float*)d_in[7];
    const float* c_mlp  = (const float*)d_in[8];
    float* out = (float*)d_out;
    char* ws = (char*)d_ws;
    const size_t MB = 1024 * 1024;

    short* wqkv_bf  = (short*)(ws + 0 * MB);    // [cvt -> QKV]
    short* wproj_bf = (short*)(ws + 6 * MB);    // [cvt -> proj]
    short* wfc_bf   = (short*)(ws + 8 * MB);    // [cvt -> FC]
    short* wmlp_bf  = (short*)(ws + 16 * MB);   // [cvt -> MLP]
    short* y_bf     = (short*)(ws + 24 * MB);   // [ln1 -> QKV], [ln2 -> FC]
    short* q_bf     = (short*)(ws + 32 * MB);   // [QKV -> attn]
    short* k_bf     = (short*)(ws + 40 * MB);   // [QKV -> attn]
    short* vT_bf    = (short*)(ws + 48 * MB);   // [QKV -> attn]
    short* att_bf   = (short*)(ws + 56 * MB);   // [attn -> proj]
    float* a0       = (float*)(ws + 64 * MB);   // [proj -> expmap1]
    float* a1       = (float*)(ws + 80 * MB);   // [proj -> expmap1]
    float* x1       = (float*)(ws + 40 * MB);   // [expmap1 -> expmap2] (over k,vT)
    short* g_bf     = (short*)(ws + 56 * MB);   // [FC -> MLP] 32MB (over att,a0,a1[0:8])
    float* h0       = (float*)(ws + 0 * MB);    // [MLP -> expmap2] (over weights)
    float* h1       = (float*)(ws + 24 * MB);   // [MLP -> expmap2] (over y_bf,q_bf)

    cvt_kernel<<<3072, 256, 0, stream>>>(w_qkv, wqkv_bf, 3072 * 1024 / 4);
    cvt_kernel<<<1024, 256, 0, stream>>>(w_proj, wproj_bf, 1024 * 1024 / 4);
    cvt_kernel<<<4096, 256, 0, stream>>>(w_fc, wfc_bf, 4096 * 1024 / 4);
    cvt_kernel<<<4096, 256, 0, stream>>>(w_mlp, wmlp_bf, 1024 * 4096 / 4);

    ln_kernel<<<4096, 256, 0, stream>>>(x, ln1_g, y_bf);
    gemm8p<0><<<dim3(16, 12), 512, 0, stream>>>(y_bf, wqkv_bf, 4096, 3072, 1024,
                                                q_bf, k_bf, vT_bf);
    attn_kernel<<<dim3(32, 32), 256, 0, stream>>>(q_bf, k_bf, vT_bf, att_bf);
    gemm_bt<1><<<dim3(32, 8, 2), 256, 0, stream>>>(att_bf, wproj_bf, 4096, 1024, 1024, 512,
                                                   a0, a1, nullptr);
    expmap_kernel<<<16384, 256, 0, stream>>>(x, a0, a1, c_attn, x1);
    ln_kernel<<<4096, 256, 0, stream>>>(x1, ln2_g, y_bf);
    gemm8p<2><<<dim3(16, 16), 512, 0, stream>>>(y_bf, wfc_bf, 4096, 4096, 1024,
                                                g_bf, nullptr, nullptr);
    gemm_bt<1><<<dim3(32, 8, 2), 256, 0, stream>>>(g_bf, wmlp_bf, 4096, 1024, 4096, 2048,
                                                   h0, h1, nullptr);
    expmap_kernel<<<16384, 256, 0, stream>>>(x1, h0, h1, c_mlp, out);
}

// Round 16
// 292.861 us; speedup vs baseline: 1.2682x; 1.1721x over previous
//
#include <hip/hip_runtime.h>
#include <hip/hip_bf16.h>

typedef __attribute__((ext_vector_type(8))) short bf16x8;
typedef __attribute__((ext_vector_type(4))) float f32x4;

typedef const __attribute__((address_space(1))) void gv_t;
typedef __attribute__((address_space(3))) void lv_t;
#define GLL16(g, l) __builtin_amdgcn_global_load_lds((gv_t*)(g), (lv_t*)(l), 16, 0, 0)

#define WAITV8()  asm volatile("s_waitcnt vmcnt(8)" ::: "memory")
#define WAITV0()  asm volatile("s_waitcnt vmcnt(0)" ::: "memory")
#define WAITL0()  asm volatile("s_waitcnt lgkmcnt(0)" ::: "memory")
#define SCHEDB()  __builtin_amdgcn_sched_barrier(0)
#define BARRAW()  __builtin_amdgcn_s_barrier()

__device__ __forceinline__ short f2bf(float f) {
    __hip_bfloat16 h = __float2bfloat16(f);
    return *reinterpret_cast<short*>(&h);
}

__device__ __forceinline__ float wred(float v) {
    #pragma unroll
    for (int m = 1; m < 64; m <<= 1) v += __shfl_xor(v, m);
    return v;
}

// ---------------- fp32 -> bf16 convert, all 4 weights in one launch ----------------
__global__ __launch_bounds__(256) void cvt4_kernel(const float* __restrict__ i0, short* __restrict__ o0, int n0,
                                                   const float* __restrict__ i1, short* __restrict__ o1, int n1,
                                                   const float* __restrict__ i2, short* __restrict__ o2, int n2,
                                                   const float* __restrict__ i3, short* __restrict__ o3, int n3) {
    const int stride = gridDim.x * 256;
    for (int seg = 0; seg < 4; ++seg) {
        const float* in = (seg == 0) ? i0 : (seg == 1) ? i1 : (seg == 2) ? i2 : i3;
        short* out      = (seg == 0) ? o0 : (seg == 1) ? o1 : (seg == 2) ? o2 : o3;
        const int n4    = (seg == 0) ? n0 : (seg == 1) ? n1 : (seg == 2) ? n2 : n3;
        for (int i = blockIdx.x * 256 + threadIdx.x; i < n4; i += stride) {
            float4 v = ((const float4*)in)[i];
            short4 o;
            o.x = f2bf(v.x); o.y = f2bf(v.y); o.z = f2bf(v.z); o.w = f2bf(v.w);
            ((short4*)out)[i] = o;
        }
    }
}

// ---------------- LayerNorm (fp32 in, bf16 out), row = 1024 ----------------
__global__ __launch_bounds__(256) void ln_kernel(const float* __restrict__ x,
                                                 const float* __restrict__ g,
                                                 short* __restrict__ y) {
    const int row = blockIdx.x, tid = threadIdx.x;
    const float4 v = ((const float4*)(x + (size_t)row * 1024))[tid];
    float s = v.x + v.y + v.z + v.w;
    float s2 = v.x * v.x + v.y * v.y + v.z * v.z + v.w * v.w;
    #pragma unroll
    for (int m = 1; m < 64; m <<= 1) { s += __shfl_xor(s, m); s2 += __shfl_xor(s2, m); }
    __shared__ float rs[4], rs2[4];
    if ((tid & 63) == 0) { rs[tid >> 6] = s; rs2[tid >> 6] = s2; }
    __syncthreads();
    s = rs[0] + rs[1] + rs[2] + rs[3];
    s2 = rs2[0] + rs2[1] + rs2[2] + rs2[3];
    const float mean = s * (1.0f / 1024.0f);
    const float var = s2 * (1.0f / 1024.0f) - mean * mean;
    const float r = rsqrtf(var + 1e-5f);
    const float4 gg = ((const float4*)g)[tid];
    short4 o;
    o.x = f2bf((v.x - mean) * r * gg.x);
    o.y = f2bf((v.y - mean) * r * gg.y);
    o.z = f2bf((v.z - mean) * r * gg.z);
    o.w = f2bf((v.w - mean) * r * gg.w);
    ((short4*)y)[(size_t)row * 256 + tid] = o;
}

// ---------------- GEMM: C[M,N] = A[M,K] * B[N,K]^T, bf16 in (r12-verified) ---------
// 128x128, 4 waves, BK=64 double-buffered, counted vmcnt(8) across raw barriers,
// XOR-swizzled staging (0 bank conflicts), XCD-chunked block swizzle (requires
// gridDim.x==32, gridDim.y%4==0).  Split-K via blockIdx.z.
// EPI 0: QKV split -> q (1/8), k, vT   EPI 1: fp32 (o0/o1 per z)   EPI 2: GELU bf16
template <int EPI>
__global__ __launch_bounds__(256, 2) void gemm_bt(const short* __restrict__ A,
                                                  const short* __restrict__ Bw,
                                                  int M, int N, int LDK, int KL,
                                                  void* __restrict__ o0,
                                                  void* __restrict__ o1,
                                                  void* __restrict__ o2) {
    __shared__ __align__(16) short As[2][128 * 64];   // 32 KB
    __shared__ __align__(16) short Bs[2][128 * 64];   // 32 KB
    const int tid = threadIdx.x;
    const int wid = tid >> 6, lane = tid & 63;
    const int wm = wid >> 1, wn = wid & 1;
    const int col = lane & 15, grp = lane >> 4;
    const int r8 = lane >> 3, s8 = lane & 7;
    const int orig = blockIdx.x + (int)gridDim.x * blockIdx.y;
    const int xcd = orig & 7, idx = orig >> 3;
    const int NC = gridDim.y >> 2;
    const int mt = ((xcd >> 2) << 4) + (idx & 15);
    const int nt = (xcd & 3) * NC + (idx >> 4);
    const int m0 = mt * 128, n0 = nt * 128;
    const int z = blockIdx.z;
    f32x4 acc[4][4] = {};
    const short* ga = A + (size_t)m0 * LDK + (size_t)z * KL;
    const short* gb = Bw + (size_t)n0 * LDK + (size_t)z * KL;

#define GSTAGE(b_, t_) do {                                                     \
        const int k0_ = (t_) * 64;                                              \
        _Pragma("unroll")                                                       \
        for (int c = 0; c < 4; ++c) {                                           \
            const int row = c * 32 + wid * 8 + r8;                              \
            const int slot = s8 ^ (row & 7);                                    \
            GLL16(ga + (size_t)row * LDK + k0_ + slot * 8,                      \
                  (char*)&As[b_][0] + c * 4096 + wid * 1024);                   \
            GLL16(gb + (size_t)row * LDK + k0_ + slot * 8,                      \
                  (char*)&Bs[b_][0] + c * 4096 + wid * 1024);                   \
        }                                                                       \
    } while (0)

    const int NT = KL >> 6;
    GSTAGE(0, 0);
    if (NT > 1) { GSTAGE(1, 1); WAITV8(); } else { WAITV0(); }
    SCHEDB();
    BARRAW();
    int cur = 0;
    for (int t = 0; t < NT; ++t) {
        const char* At = (const char*)&As[cur][0];
        const char* Bt = (const char*)&Bs[cur][0];
        bf16x8 af[2][4], bfr[2][4];
        #pragma unroll
        for (int s = 0; s < 2; ++s)
            #pragma unroll
            for (int i = 0; i < 4; ++i) {
                const int rowA = wm * 64 + i * 16 + col;
                const int rowB = wn * 64 + i * 16 + col;
                af[s][i]  = *(const bf16x8*)(At + rowA * 128 + (((s * 4 + grp) ^ (rowA & 7)) << 4));
                bfr[s][i] = *(const bf16x8*)(Bt + rowB * 128 + (((s * 4 + grp) ^ (rowB & 7)) << 4));
            }
        WAITL0(); SCHEDB();      // reads retired -> WAR-safe to overwrite after barrier
        BARRAW();
        if (t + 2 < NT) GSTAGE(cur, t + 2);
        #pragma unroll
        for (int s = 0; s < 2; ++s)
            #pragma unroll
            for (int mi = 0; mi < 4; ++mi)
                #pragma unroll
                for (int ni = 0; ni < 4; ++ni)
                    acc[mi][ni] = __builtin_amdgcn_mfma_f32_16x16x32_bf16(af[s][mi], bfr[s][ni], acc[mi][ni], 0, 0, 0);
        if (t + 1 < NT) {
            if (t + 2 < NT) { WAITV8(); } else { WAITV0(); }
            SCHEDB();
            BARRAW();
        }
        cur ^= 1;
    }
#undef GSTAGE
    #pragma unroll
    for (int mi = 0; mi < 4; ++mi) {
        #pragma unroll
        for (int ni = 0; ni < 4; ++ni) {
            #pragma unroll
            for (int i = 0; i < 4; ++i) {
                const int m = m0 + wm * 64 + mi * 16 + grp * 4 + i;
                const int n = n0 + wn * 64 + ni * 16 + col;
                const float v = acc[mi][ni][i];
                if (EPI == 0) {
                    const int b = m >> 11, t = m & 2047;
                    const int which = n >> 10, nn = n & 1023;
                    const int h = nn >> 6, d = nn & 63;
                    const size_t bh = (size_t)(b * 16 + h);
                    if (which == 0)
                        ((short*)o0)[(bh * 2048 + t) * 64 + d] = f2bf(v * 0.125f);
                    else if (which == 1)
                        ((short*)o1)[(bh * 2048 + t) * 64 + d] = f2bf(v);
                    else
                        ((short*)o2)[(bh * 64 + d) * 2048 + t] = f2bf(v);
                } else if (EPI == 1) {
                    float* dst = (z == 0) ? (float*)o0 : (float*)o1;
                    dst[(size_t)m * N + n] = v;
                } else {
                    const float gl = 0.5f * v * (1.0f + erff(v * 0.70710678118654752f));
                    ((short*)o0)[(size_t)m * N + n] = f2bf(gl);
                }
            }
        }
    }
}

// ---------------- Flash attention, causal, LDS-staged K/V, 64-row q-tile ----------
// (r10/r12-verified)
__global__ __launch_bounds__(256, 3) void attn_kernel(const short* __restrict__ Q,
                                                      const short* __restrict__ Kg,
                                                      const short* __restrict__ VT,
                                                      short* __restrict__ Y) {
    __shared__ __align__(16) short Ks[2][4096];
    __shared__ __align__(16) short Vs[2][4096];
    __shared__ __align__(16) short Plds[4][16 * 72];
    const int j = 31 - blockIdx.x;
    const int bh = blockIdx.y;
    const int tid = threadIdx.x, wid = tid >> 6, lane = tid & 63;
    const int ql = lane & 15, g = lane >> 4;
    const int r8 = lane >> 3, s8 = lane & 7;
    const int q0s = j * 64 + wid * 16;
    const int lt = j;
    const short* Qb = Q + (size_t)bh * 2048 * 64;
    const short* Kb = Kg + (size_t)bh * 2048 * 64;
    const short* Vb = VT + (size_t)bh * 64 * 2048;
    short* Pw = &Plds[wid][0];

    bf16x8 qf0 = *(const bf16x8*)&Qb[(size_t)(q0s + ql) * 64 + 8 * g];
    bf16x8 qf1 = *(const bf16x8*)&Qb[(size_t)(q0s + ql) * 64 + 32 + 8 * g];
    f32x4 o[4] = {};
    float m = -1e30f, lsum = 0.0f;

#define STAGE(b_, kt_) do {                                                      \
        const int kbase_ = (kt_) * 64;                                           \
        _Pragma("unroll")                                                        \
        for (int c = 0; c < 2; ++c) {                                            \
            const int row = c * 32 + wid * 8 + r8;                               \
            const int slot = s8 ^ (row & 7);                                     \
            GLL16(Kb + (size_t)(kbase_ + row) * 64 + slot * 8,                   \
                  (char*)&Ks[b_][0] + c * 4096 + wid * 1024);                    \
            GLL16(Vb + (size_t)row * 2048 + kbase_ + slot * 8,                   \
                  (char*)&Vs[b_][0] + c * 4096 + wid * 1024);                    \
        }                                                                        \
    } while (0)

    STAGE(0, 0);
    __syncthreads();
    int buf = 0;
    for (int kt = 0; kt <= lt; ++kt) {
        if (kt < lt) STAGE(buf ^ 1, kt + 1);
        const int kbase = kt * 64;
        const short* Kt = &Ks[buf][0];
        const short* Vt = &Vs[buf][0];
        bf16x8 kf[4][2];
        #pragma unroll
        for (int kb = 0; kb < 4; ++kb) {
            const int row = 16 * kb + ql;
            const int x = row & 7;
            kf[kb][0] = *(const bf16x8*)((const char*)Kt + row * 128 + ((g ^ x) << 4));
            kf[kb][1] = *(const bf16x8*)((const char*)Kt + row * 128 + (((4 + g) ^ x) << 4));
        }
        f32x4 s[4];
        #pragma unroll
        for (int kb = 0; kb < 4; ++kb) {
            f32x4 z = {0.f, 0.f, 0.f, 0.f};
            z = __builtin_amdgcn_mfma_f32_16x16x32_bf16(kf[kb][0], qf0, z, 0, 0, 0);
            z = __builtin_amdgcn_mfma_f32_16x16x32_bf16(kf[kb][1], qf1, z, 0, 0, 0);
            s[kb] = z;
        }
        if (kbase + 63 > q0s) {
            #pragma unroll
            for (int kb = 0; kb < 4; ++kb)
                #pragma unroll
                for (int r = 0; r < 4; ++r)
                    if (kbase + 16 * kb + 4 * g + r > q0s + ql) s[kb][r] = -1e30f;
        }
        float t0 = fmaxf(fmaxf(s[0][0], s[0][1]), fmaxf(s[0][2], s[0][3]));
        float t1 = fmaxf(fmaxf(s[1][0], s[1][1]), fmaxf(s[1][2], s[1][3]));
        float t2 = fmaxf(fmaxf(s[2][0], s[2][1]), fmaxf(s[2][2], s[2][3]));
        float t3 = fmaxf(fmaxf(s[3][0], s[3][1]), fmaxf(s[3][2], s[3][3]));
        float tmax = fmaxf(fmaxf(t0, t1), fmaxf(t2, t3));
        tmax = fmaxf(tmax, __shfl_xor(tmax, 16));
        tmax = fmaxf(tmax, __shfl_xor(tmax, 32));
        const float mnew = fmaxf(m, tmax);
        const float sc = __expf(m - mnew);
        m = mnew;
        float rsum = 0.0f;
        #pragma unroll
        for (int kb = 0; kb < 4; ++kb) {
            const float e0 = __expf(s[kb][0] - mnew);
            const float e1 = __expf(s[kb][1] - mnew);
            const float e2 = __expf(s[kb][2] - mnew);
            const float e3 = __expf(s[kb][3] - mnew);
            rsum += (e0 + e1) + (e2 + e3);
            short4 pk;
            pk.x = f2bf(e0); pk.y = f2bf(e1); pk.z = f2bf(e2); pk.w = f2bf(e3);
            *(short4*)&Pw[ql * 72 + 16 * kb + 4 * g] = pk;
        }
        rsum += __shfl_xor(rsum, 16);
        rsum += __shfl_xor(rsum, 32);
        lsum = lsum * sc + rsum;
        #pragma unroll
        for (int nf = 0; nf < 4; ++nf)
            #pragma unroll
            for (int r = 0; r < 4; ++r) o[nf][r] *= sc;
        const bf16x8 pb0 = *(const bf16x8*)&Pw[ql * 72 + 8 * g];
        const bf16x8 pb1 = *(const bf16x8*)&Pw[ql * 72 + 32 + 8 * g];
        #pragma unroll
        for (int nf = 0; nf < 4; ++nf) {
            const int row = 16 * nf + ql;
            const int x = row & 7;
            bf16x8 v0 = *(const bf16x8*)((const char*)Vt + row * 128 + ((g ^ x) << 4));
            bf16x8 v1 = *(const bf16x8*)((const char*)Vt + row * 128 + (((4 + g) ^ x) << 4));
            o[nf] = __builtin_amdgcn_mfma_f32_16x16x32_bf16(v0, pb0, o[nf], 0, 0, 0);
            o[nf] = __builtin_amdgcn_mfma_f32_16x16x32_bf16(v1, pb1, o[nf], 0, 0, 0);
        }
        __syncthreads();
        buf ^= 1;
    }
#undef STAGE
    const int b = bh >> 4, h = bh & 15;
    const float inv = 1.0f / lsum;
    const size_t rowoff = ((size_t)b * 2048 + q0s + ql) * 1024 + h * 64;
    #pragma unroll
    for (int nf = 0; nf < 4; ++nf) {
        short4 w;
        w.x = f2bf(o[nf][0] * inv);
        w.y = f2bf(o[nf][1] * inv);
        w.z = f2bf(o[nf][2] * inv);
        w.w = f2bf(o[nf][3] * inv);
        *(short4*)&Y[rowoff + 16 * nf + 4 * g] = w;
    }
}

// ---------------- Hyperbolic residual: out = expmap(x, va+vb, c), per-head wave ---
__global__ __launch_bounds__(256) void expmap_kernel(const float* __restrict__ x,
                                                     const float* __restrict__ va,
                                                     const float* __restrict__ vb,
                                                     const float* __restrict__ carr,
                                                     float* __restrict__ out) {
    const int blk = blockIdx.x;
    const int row = blk >> 2;
    const int head = (blk & 3) * 4 + (threadIdx.x >> 6);
    const int lane = threadIdx.x & 63;
    const size_t idx = (size_t)row * 1024 + head * 64 + lane;
    float c = carr[head];
    c = fminf(fmaxf(c, 1e-4f), 1.0f);
    const float xe = x[idx], ve = va[idx] + vb[idx];
    const float xn = wred(xe * xe);
    const float vns = wred(ve * ve);
    const float vn = sqrtf(vns + 1e-9f);
    const float sf = 2.0f / (1.0f + c * xn + 1e-9f);
    const float targ = fabsf(0.5f * c * sf * vns);
    const float coeff = (1.0f / (sqrtf(c + 1e-9f) + 1e-9f)) * tanhf(sqrtf(targ + 1e-9f));
    const float ye = coeff * ve / (vn + 1e-9f);
    const float yn = wred(ye * ye);
    const float ip = wred(xe * ye);
    const float num = (1.0f + 2.0f * c * ip + c * yn) * xe + (1.0f - c * xn) * ye;
    const float den = 1.0f + 2.0f * c * ip + c * c * xn * yn;
    out[idx] = num / (den + 1e-9f);
}

extern "C" void kernel_launch(void* const* d_in, const int* in_sizes, int n_in,
                              void* d_out, int out_size, void* d_ws, size_t ws_size,
                              hipStream_t stream) {
    (void)in_sizes; (void)n_in; (void)out_size; (void)ws_size;
    const float* x      = (const float*)d_in[0];
    const float* ln1_g  = (const float*)d_in[1];
    const float* w_qkv  = (const float*)d_in[2];
    const float* w_proj = (const float*)d_in[3];
    const float* c_attn = (const float*)d_in[4];
    const float* ln2_g  = (const float*)d_in[5];
    const float* w_fc   = (const float*)d_in[6];
    const float* w_mlp  = (const float*)d_in[7];
    const float* c_mlp  = (const float*)d_in[8];
    float* out = (float*)d_out;
    char* ws = (char*)d_ws;
    const size_t MB = 1024 * 1024;

    short* wqkv_bf  = (short*)(ws + 0 * MB);    // [cvt -> QKV]
    short* wproj_bf = (short*)(ws + 6 * MB);    // [cvt -> proj]
    short* wfc_bf   = (short*)(ws + 8 * MB);    // [cvt -> FC]
    short* wmlp_bf  = (short*)(ws + 16 * MB);   // [cvt -> MLP]
    short* y_bf     = (short*)(ws + 24 * MB);   // [ln1 -> QKV], [ln2 -> FC]
    short* q_bf     = (short*)(ws + 32 * MB);   // [QKV -> attn]
    short* k_bf     = (short*)(ws + 40 * MB);   // [QKV -> attn]
    short* vT_bf    = (short*)(ws + 48 * MB);   // [QKV -> attn]
    short* att_bf   = (short*)(ws + 56 * MB);   // [attn -> proj]
    float* a0       = (float*)(ws + 64 * MB);   // [proj -> expmap1]
    float* a1       = (float*)(ws + 80 * MB);   // [proj -> expmap1]
    float* x1       = (float*)(ws + 40 * MB);   // [expmap1 -> expmap2] (over k,vT)
    short* g_bf     = (short*)(ws + 56 * MB);   // [FC -> MLP] 32MB (over att,a0,a1[0:8])
    float* h0       = (float*)(ws + 0 * MB);    // [MLP -> expmap2] (over weights)
    float* h1       = (float*)(ws + 24 * MB);   // [MLP -> expmap2] (over y_bf,q_bf)

    cvt4_kernel<<<2048, 256, 0, stream>>>(w_qkv, wqkv_bf, 3072 * 1024 / 4,
                                          w_proj, wproj_bf, 1024 * 1024 / 4,
                                          w_fc, wfc_bf, 4096 * 1024 / 4,
                                          w_mlp, wmlp_bf, 1024 * 4096 / 4);

    ln_kernel<<<4096, 256, 0, stream>>>(x, ln1_g, y_bf);
    gemm_bt<0><<<dim3(32, 24, 1), 256, 0, stream>>>(y_bf, wqkv_bf, 4096, 3072, 1024, 1024,
                                                    q_bf, k_bf, vT_bf);
    attn_kernel<<<dim3(32, 32), 256, 0, stream>>>(q_bf, k_bf, vT_bf, att_bf);
    gemm_bt<1><<<dim3(32, 8, 2), 256, 0, stream>>>(att_bf, wproj_bf, 4096, 1024, 1024, 512,
                                                   a0, a1, nullptr);
    expmap_kernel<<<16384, 256, 0, stream>>>(x, a0, a1, c_attn, x1);
    ln_kernel<<<4096, 256, 0, stream>>>(x1, ln2_g, y_bf);
    gemm_bt<2><<<dim3(32, 32, 1), 256, 0, stream>>>(y_bf, wfc_bf, 4096, 4096, 1024, 1024,
                                                    g_bf, nullptr, nullptr);
    gemm_bt<1><<<dim3(32, 8, 2), 256, 0, stream>>>(g_bf, wmlp_bf, 4096, 1024, 4096, 2048,
                                                   h0, h1, nullptr);
    expmap_kernel<<<16384, 256, 0, stream>>>(x1, h0, h1, c_mlp, out);
}